// Round 1
// baseline (11350.690 us; speedup 1.0000x reference)
//
#include <hip/hip_runtime.h>
#include <hip/hip_bf16.h>

// GNNClassifier: 2x GRU(scan) -> GAT attention -> LN -> MHA -> pool -> FC
// B=16 T=1024 IN=64 H=256 G3=768 K=4 F=64 NH=4 HD=64 C=2

#define B_ 16
#define T_ 1024
#define IN_ 64
#define H_ 256
#define G3_ 768

typedef _Float16 f16x8 __attribute__((ext_vector_type(8)));
typedef float f32x4 __attribute__((ext_vector_type(4)));

__device__ __forceinline__ float sigmoidf_(float x) { return 1.f / (1.f + __expf(-x)); }
__device__ __forceinline__ float tanh_fast(float x) {
    float t = __expf(-2.f * fabsf(x));
    float r = (1.f - t) / (1.f + t);
    return x >= 0.f ? r : -r;
}

// ---------------- generic tiled f32 GEMM: Y[M][N] = X[M][Kd] @ W[N][Kd]^T + bias ----------------
__global__ __launch_bounds__(256) void gemm_bias(
    const float* __restrict__ X, const float* __restrict__ W,
    const float* __restrict__ bias, float* __restrict__ Y,
    int M, int N, int Kd)
{
    __shared__ float As[16][68];   // [k][m]
    __shared__ float Bs[16][68];   // [k][n]
    const int tid = threadIdx.x;
    const int bm = blockIdx.y * 64, bn = blockIdx.x * 64;
    const int tx = tid & 15, ty = tid >> 4;
    const int lr = tid >> 2, lk = (tid & 3) * 4;
    float acc[4][4] = {};
    for (int k0 = 0; k0 < Kd; k0 += 16) {
        float4 va = *(const float4*)(X + (size_t)(bm + lr) * Kd + k0 + lk);
        float4 vb = *(const float4*)(W + (size_t)(bn + lr) * Kd + k0 + lk);
        As[lk + 0][lr] = va.x; As[lk + 1][lr] = va.y; As[lk + 2][lr] = va.z; As[lk + 3][lr] = va.w;
        Bs[lk + 0][lr] = vb.x; Bs[lk + 1][lr] = vb.y; Bs[lk + 2][lr] = vb.z; Bs[lk + 3][lr] = vb.w;
        __syncthreads();
        #pragma unroll
        for (int k = 0; k < 16; ++k) {
            float4 a = *(const float4*)&As[k][ty * 4];
            float4 b = *(const float4*)&Bs[k][tx * 4];
            float av[4] = {a.x, a.y, a.z, a.w};
            float bv[4] = {b.x, b.y, b.z, b.w};
            #pragma unroll
            for (int i = 0; i < 4; ++i)
                #pragma unroll
                for (int j = 0; j < 4; ++j)
                    acc[i][j] += av[i] * bv[j];
        }
        __syncthreads();
    }
    float4 bv4 = bias ? *(const float4*)(bias + bn + tx * 4) : make_float4(0.f, 0.f, 0.f, 0.f);
    #pragma unroll
    for (int i = 0; i < 4; ++i) {
        float4 ov = make_float4(acc[i][0] + bv4.x, acc[i][1] + bv4.y, acc[i][2] + bv4.z, acc[i][3] + bv4.w);
        *(float4*)(Y + (size_t)(bm + ty * 4 + i) * N + bn + tx * 4) = ov;
    }
}

// ---------------- GRU scan: one block, all 16 batches, MFMA 16x16x32 f16 ----------------
// Step GEMM: gh[16][768] = h[16][256] @ w_hh[768][256]^T.  M=batch, N=gate-row, K=hidden.
// wave w owns gate units j in [32w, 32w+32): tiles (g=r/z/n) x (q=0/1 sub-tile of 16 units).
// A/B frags built with identical (hi,i)->k mapping => correct for any HW k-permutation.
// Verified C/D layout: m=(lane>>4)*4+reg, n=lane&15.
__global__ __launch_bounds__(512) void gru_scan(
    const float* __restrict__ xp,   // [B][T][768] (b_ih already added)
    const float* __restrict__ w_hh, // [768][256]
    const float* __restrict__ b_hh, // [768]
    float* __restrict__ ys)         // [B][T][256]
{
    __shared__ _Float16 h16[16][264]; // [batch][k], padded row 264 to spread banks
    const int tid = threadIdx.x;
    const int lane = tid & 63;
    const int wv = tid >> 6;     // wave 0..7
    const int col = lane & 15;   // tile col (m for A, n for B/D)
    const int hi = lane >> 4;    // 0..3

    f16x8 bf[3][2][8];
    float bias_[3][2];
    #pragma unroll
    for (int g = 0; g < 3; ++g) {
        #pragma unroll
        for (int q = 0; q < 2; ++q) {
            const int n = g * 256 + wv * 32 + q * 16 + col;
            bias_[g][q] = b_hh[n];
            #pragma unroll
            for (int c = 0; c < 8; ++c) {
                const float* src = w_hh + (size_t)n * 256 + c * 32 + hi * 8;
                f16x8 v;
                #pragma unroll
                for (int i = 0; i < 8; ++i) v[i] = (_Float16)src[i];
                bf[g][q][c] = v;
            }
        }
    }
    float hold[2][4] = {};
    for (int idx = tid; idx < 16 * 264; idx += 512) (&h16[0][0])[idx] = (_Float16)0.f;
    __syncthreads();

    for (int t = 0; t < T_; ++t) {
        // prefetch xp for this step (independent of h -> overlaps MFMAs)
        float xv[3][2][4];
        #pragma unroll
        for (int g = 0; g < 3; ++g)
            #pragma unroll
            for (int q = 0; q < 2; ++q) {
                const int n = g * 256 + wv * 32 + q * 16 + col;
                #pragma unroll
                for (int j = 0; j < 4; ++j) {
                    const int b = hi * 4 + j;
                    xv[g][q][j] = xp[((size_t)b * T_ + t) * G3_ + n];
                }
            }
        f32x4 acc[3][2] = {};
        #pragma unroll
        for (int c = 0; c < 8; ++c) {
            f16x8 a = *(const f16x8*)(&h16[col][c * 32 + hi * 8]);
            #pragma unroll
            for (int g = 0; g < 3; ++g)
                #pragma unroll
                for (int q = 0; q < 2; ++q)
                    acc[g][q] = __builtin_amdgcn_mfma_f32_16x16x32_f16(a, bf[g][q][c], acc[g][q], 0, 0, 0);
        }
        __syncthreads();  // all reads of h16 complete before overwrite
        #pragma unroll
        for (int q = 0; q < 2; ++q) {
            const int unit = wv * 32 + q * 16 + col;
            #pragma unroll
            for (int j = 0; j < 4; ++j) {
                const int b = hi * 4 + j;
                float ghr = acc[0][q][j] + bias_[0][q];
                float ghz = acc[1][q][j] + bias_[1][q];
                float ghn = acc[2][q][j] + bias_[2][q];
                float r = sigmoidf_(xv[0][q][j] + ghr);
                float z = sigmoidf_(xv[1][q][j] + ghz);
                float nn = tanh_fast(xv[2][q][j] + r * ghn);
                float hv = (1.f - z) * nn + z * hold[q][j];
                hold[q][j] = hv;
                ys[((size_t)b * T_ + t) * H_ + unit] = hv;
                h16[b][unit] = (_Float16)hv;
            }
        }
        __syncthreads();  // h16 ready for next step
    }
}

// ---------------- gat_W (K,H,F) -> W2[(k*64+f)][d] ----------------
__global__ void gatw_t(const float* __restrict__ gw, float* __restrict__ W2)
{
    int idx = blockIdx.x * 256 + threadIdx.x; // 65536
    int n = idx >> 8, d = idx & 255;
    W2[idx] = gw[(size_t)(n >> 6) * 16384 + (size_t)d * 64 + (n & 63)];
}

// ---------------- e1/e2: [b][k][t] = sum_f hk[b][t][k*64+f] * a{1,2}[k][f] ----------------
__global__ __launch_bounds__(256) void gat_e(
    const float* __restrict__ hk, const float* __restrict__ ga,
    float* __restrict__ e1, float* __restrict__ e2)
{
    __shared__ float tile[128][65];
    __shared__ float a1s[64], a2s[64];
    const int tt = blockIdx.x, k = blockIdx.y, b = blockIdx.z; // grid (8,4,16)
    const int tid = threadIdx.x;
    if (tid < 64) { a1s[tid] = ga[k * 128 + tid]; a2s[tid] = ga[k * 128 + 64 + tid]; }
    #pragma unroll
    for (int rep = 0; rep < 32; ++rep) {
        int idx = rep * 256 + tid; int tl = idx >> 6, f = idx & 63;
        tile[tl][f] = hk[((size_t)(b * 1024 + tt * 128 + tl)) * 256 + k * 64 + f];
    }
    __syncthreads();
    if (tid < 128) {
        float s1 = 0.f, s2 = 0.f;
        #pragma unroll 8
        for (int f = 0; f < 64; ++f) {
            float hv = tile[tid][f];
            s1 += hv * a1s[f]; s2 += hv * a2s[f];
        }
        const size_t o = (size_t)(b * 4 + k) * 1024 + tt * 128 + tid;
        e1[o] = s1; e2[o] = s2;
    }
}

// ---------------- GAT attention: out[b][t][k*64+f] = sum_s softmax_s(leaky(e1[t]+e2[s])) * hk[b][s][k*64+f] ----
__global__ __launch_bounds__(256) void gat_attn(
    const float* __restrict__ hk, const float* __restrict__ e1,
    const float* __restrict__ e2, float* __restrict__ outp)
{
    __shared__ float hks[64][64];
    __shared__ float wsld[64][65];
    __shared__ float e2s[64];
    __shared__ float e1s[64];
    __shared__ float ms[64];
    __shared__ float ls[64];
    const int tt = blockIdx.x, k = blockIdx.y, b = blockIdx.z; // grid (16,4,16)
    const int tid = threadIdx.x;
    const int t0 = tt * 64;
    const float* e2row = e2 + (size_t)(b * 4 + k) * 1024;
    if (tid < 64) { e1s[tid] = e1[(size_t)(b * 4 + k) * 1024 + t0 + tid]; ls[tid] = 0.f; }
    __syncthreads();
    // pass A: exact row max (scores are cheap: e1[t]+e2[s])
    {
        const int t = tid & 63, grp = tid >> 6;
        const float ev1 = e1s[t];
        float m = -3.4e38f;
        for (int s = grp; s < 1024; s += 4) {
            float e = ev1 + e2row[s];
            e = (e > 0.f) ? e : 0.2f * e;
            m = fmaxf(m, e);
        }
        wsld[t][grp] = m;
    }
    __syncthreads();
    if (tid < 64) ms[tid] = fmaxf(fmaxf(wsld[tid][0], wsld[tid][1]), fmaxf(wsld[tid][2], wsld[tid][3]));
    __syncthreads();
    float acc[16] = {};
    const int tB = tid & 63, fq = tid >> 6;
    const int tA = tid >> 2, sq = tid & 3;
    const float e1A = e1s[tA];
    const float mA = ms[tA];
    for (int st = 0; st < 16; ++st) {
        #pragma unroll
        for (int rep = 0; rep < 16; ++rep) {
            int idx = rep * 256 + tid; int sl = idx >> 6, f = idx & 63;
            hks[sl][f] = hk[((size_t)(b * 1024 + st * 64 + sl)) * 256 + k * 64 + f];
        }
        if (tid < 64) e2s[tid] = e2row[st * 64 + tid];
        __syncthreads();
        {
            float lsum = 0.f;
            #pragma unroll
            for (int i = 0; i < 16; ++i) {
                int s = sq * 16 + i;
                float e = e1A + e2s[s];
                e = (e > 0.f) ? e : 0.2f * e;
                float wvv = __expf(e - mA);
                wsld[tA][s] = wvv;
                lsum += wvv;
            }
            lsum += __shfl_xor(lsum, 1);
            lsum += __shfl_xor(lsum, 2);
            if (sq == 0) ls[tA] += lsum;
        }
        __syncthreads();
        #pragma unroll 8
        for (int i = 0; i < 64; ++i) {
            float wvv = wsld[tB][i];
            const float4 v0 = *(const float4*)&hks[i][fq * 16 + 0];
            const float4 v1 = *(const float4*)&hks[i][fq * 16 + 4];
            const float4 v2 = *(const float4*)&hks[i][fq * 16 + 8];
            const float4 v3 = *(const float4*)&hks[i][fq * 16 + 12];
            acc[0] += wvv * v0.x; acc[1] += wvv * v0.y; acc[2] += wvv * v0.z; acc[3] += wvv * v0.w;
            acc[4] += wvv * v1.x; acc[5] += wvv * v1.y; acc[6] += wvv * v1.z; acc[7] += wvv * v1.w;
            acc[8] += wvv * v2.x; acc[9] += wvv * v2.y; acc[10] += wvv * v2.z; acc[11] += wvv * v2.w;
            acc[12] += wvv * v3.x; acc[13] += wvv * v3.y; acc[14] += wvv * v3.z; acc[15] += wvv * v3.w;
        }
        __syncthreads();
    }
    const float inv = 1.f / ls[tB];
    float* po = outp + ((size_t)(b * 1024 + t0 + tB)) * 256 + k * 64 + fq * 16;
    #pragma unroll
    for (int j2 = 0; j2 < 16; j2 += 4) {
        float4 ov = make_float4(acc[j2] * inv, acc[j2 + 1] * inv, acc[j2 + 2] * inv, acc[j2 + 3] * inv);
        *(float4*)(po + j2) = ov;
    }
}

// ---------------- residual + LayerNorm (in-place safe: row held in regs) ----------------
__global__ __launch_bounds__(64) void add_ln(
    const float* __restrict__ a, const float* bb,
    const float* __restrict__ gamma, const float* __restrict__ beta,
    float* outp)
{
    const int row = blockIdx.x;
    const int lane = threadIdx.x;
    const size_t base = (size_t)row * 256 + lane * 4;
    float4 va = *(const float4*)(a + base);
    float4 vb = *(const float4*)(bb + base);
    float xv[4] = {va.x + vb.x, va.y + vb.y, va.z + vb.z, va.w + vb.w};
    float s = xv[0] + xv[1] + xv[2] + xv[3];
    float s2 = xv[0] * xv[0] + xv[1] * xv[1] + xv[2] * xv[2] + xv[3] * xv[3];
    #pragma unroll
    for (int off = 32; off >= 1; off >>= 1) {
        s += __shfl_xor(s, off);
        s2 += __shfl_xor(s2, off);
    }
    const float mu = s * (1.f / 256.f);
    const float var = s2 * (1.f / 256.f) - mu * mu;
    const float rs = rsqrtf(var + 1e-5f);
    float4 g4 = *(const float4*)(gamma + lane * 4);
    float4 b4 = *(const float4*)(beta + lane * 4);
    float4 ov;
    ov.x = (xv[0] - mu) * rs * g4.x + b4.x;
    ov.y = (xv[1] - mu) * rs * g4.y + b4.y;
    ov.z = (xv[2] - mu) * rs * g4.z + b4.z;
    ov.w = (xv[3] - mu) * rs * g4.w + b4.w;
    *(float4*)(outp + base) = ov;
}

// ---------------- MHA flash attention over qkv [b][t][768] ----------------
__global__ __launch_bounds__(256) void mha_attn(const float* __restrict__ qkv, float* __restrict__ o)
{
    __shared__ float qs[64][68];
    __shared__ float kvs[64][68];   // holds K during scores, then V during PV
    __shared__ float wsld[64][65];
    __shared__ float ms[64], ls[64], cs[64];
    const int tt = blockIdx.x, h = blockIdx.y, b = blockIdx.z; // grid (16,4,16)
    const int tid = threadIdx.x;
    const int t0 = tt * 64;
    #pragma unroll
    for (int rep = 0; rep < 16; ++rep) {
        int idx = rep * 256 + tid; int tl = idx >> 6, f = idx & 63;
        qs[tl][f] = qkv[((size_t)(b * 1024 + t0 + tl)) * 768 + h * 64 + f];
    }
    if (tid < 64) { ms[tid] = -3.4e38f; ls[tid] = 0.f; }
    float acc[16] = {};
    const int tB = tid & 63, fq = tid >> 6;
    const int tA = tid >> 2, sq = tid & 3;
    __syncthreads();
    for (int st = 0; st < 16; ++st) {
        #pragma unroll
        for (int rep = 0; rep < 16; ++rep) {
            int idx = rep * 256 + tid; int sl = idx >> 6, f = idx & 63;
            kvs[sl][f] = qkv[((size_t)(b * 1024 + st * 64 + sl)) * 768 + 256 + h * 64 + f];
        }
        __syncthreads();
        float sc[16] = {};
        #pragma unroll
        for (int dc = 0; dc < 4; ++dc) {
            float4 q0 = *(const float4*)&qs[tA][dc * 16 + 0];
            float4 q1 = *(const float4*)&qs[tA][dc * 16 + 4];
            float4 q2 = *(const float4*)&qs[tA][dc * 16 + 8];
            float4 q3 = *(const float4*)&qs[tA][dc * 16 + 12];
            #pragma unroll
            for (int i = 0; i < 16; ++i) {
                const int s = sq * 16 + i;
                float4 k0 = *(const float4*)&kvs[s][dc * 16 + 0];
                float4 k1 = *(const float4*)&kvs[s][dc * 16 + 4];
                float4 k2 = *(const float4*)&kvs[s][dc * 16 + 8];
                float4 k3 = *(const float4*)&kvs[s][dc * 16 + 12];
                sc[i] += q0.x * k0.x + q0.y * k0.y + q0.z * k0.z + q0.w * k0.w
                       + q1.x * k1.x + q1.y * k1.y + q1.z * k1.z + q1.w * k1.w
                       + q2.x * k2.x + q2.y * k2.y + q2.z * k2.z + q2.w * k2.w
                       + q3.x * k3.x + q3.y * k3.y + q3.z * k3.z + q3.w * k3.w;
            }
        }
        float tmax = -3.4e38f;
        #pragma unroll
        for (int i = 0; i < 16; ++i) { sc[i] *= 0.125f; tmax = fmaxf(tmax, sc[i]); }
        tmax = fmaxf(tmax, __shfl_xor(tmax, 1));
        tmax = fmaxf(tmax, __shfl_xor(tmax, 2));
        float mold = ms[tA];
        float mnew = fmaxf(mold, tmax);
        float corrv = __expf(mold - mnew);
        float lsum = 0.f;
        #pragma unroll
        for (int i = 0; i < 16; ++i) {
            float wvv = __expf(sc[i] - mnew);
            wsld[tA][sq * 16 + i] = wvv;
            lsum += wvv;
        }
        lsum += __shfl_xor(lsum, 1);
        lsum += __shfl_xor(lsum, 2);
        if (sq == 0) { ls[tA] = ls[tA] * corrv + lsum; ms[tA] = mnew; cs[tA] = corrv; }
        __syncthreads();
        #pragma unroll
        for (int rep = 0; rep < 16; ++rep) {
            int idx = rep * 256 + tid; int sl = idx >> 6, f = idx & 63;
            kvs[sl][f] = qkv[((size_t)(b * 1024 + st * 64 + sl)) * 768 + 512 + h * 64 + f];
        }
        __syncthreads();
        {
            const float cr = cs[tB];
            #pragma unroll
            for (int j2 = 0; j2 < 16; ++j2) acc[j2] *= cr;
            #pragma unroll 8
            for (int i = 0; i < 64; ++i) {
                float wvv = wsld[tB][i];
                const float4 v0 = *(const float4*)&kvs[i][fq * 16 + 0];
                const float4 v1 = *(const float4*)&kvs[i][fq * 16 + 4];
                const float4 v2 = *(const float4*)&kvs[i][fq * 16 + 8];
                const float4 v3 = *(const float4*)&kvs[i][fq * 16 + 12];
                acc[0] += wvv * v0.x; acc[1] += wvv * v0.y; acc[2] += wvv * v0.z; acc[3] += wvv * v0.w;
                acc[4] += wvv * v1.x; acc[5] += wvv * v1.y; acc[6] += wvv * v1.z; acc[7] += wvv * v1.w;
                acc[8] += wvv * v2.x; acc[9] += wvv * v2.y; acc[10] += wvv * v2.z; acc[11] += wvv * v2.w;
                acc[12] += wvv * v3.x; acc[13] += wvv * v3.y; acc[14] += wvv * v3.z; acc[15] += wvv * v3.w;
            }
        }
        __syncthreads();
    }
    const float inv = 1.f / ls[tB];
    float* po = o + ((size_t)(b * 1024 + t0 + tB)) * 256 + h * 64 + fq * 16;
    #pragma unroll
    for (int j2 = 0; j2 < 16; j2 += 4) {
        float4 ov = make_float4(acc[j2] * inv, acc[j2 + 1] * inv, acc[j2 + 2] * inv, acc[j2 + 3] * inv);
        *(float4*)(po + j2) = ov;
    }
}

// ---------------- mean over T (pooling commuted before output projection) ----------------
__global__ __launch_bounds__(256) void pool_mean(const float* __restrict__ o, float* __restrict__ opool)
{
    const int b = blockIdx.x >> 3, chunk = blockIdx.x & 7;
    const int d = threadIdx.x;
    float s = 0.f;
    for (int t = chunk * 128; t < chunk * 128 + 128; ++t)
        s += o[((size_t)(b * 1024 + t)) * 256 + d];
    atomicAdd(&opool[b * 256 + d], s * (1.f / 1024.f));
}

// ---------------- head: out_proj(pooled) -> fc1 relu -> fc2 ----------------
__global__ __launch_bounds__(256) void head_k(
    const float* __restrict__ opool, const float* __restrict__ wout, const float* __restrict__ bout,
    const float* __restrict__ f1w, const float* __restrict__ f1b,
    const float* __restrict__ f2w, const float* __restrict__ f2b,
    float* __restrict__ outp)
{
    __shared__ float op[256], pooled[256], hid[128];
    const int b = blockIdx.x, e = threadIdx.x;
    op[e] = opool[b * 256 + e];
    __syncthreads();
    float s = bout[e];
    for (int d = 0; d < 256; d += 4) {
        float4 w4 = *(const float4*)(wout + (size_t)e * 256 + d);
        s += op[d] * w4.x + op[d + 1] * w4.y + op[d + 2] * w4.z + op[d + 3] * w4.w;
    }
    pooled[e] = s;
    __syncthreads();
    if (e < 128) {
        float s2 = f1b[e];
        for (int d = 0; d < 256; d += 4) {
            float4 w4 = *(const float4*)(f1w + (size_t)e * 256 + d);
            s2 += pooled[d] * w4.x + pooled[d + 1] * w4.y + pooled[d + 2] * w4.z + pooled[d + 3] * w4.w;
        }
        hid[e] = fmaxf(s2, 0.f);
    }
    __syncthreads();
    if (e < 2) {
        float s3 = f2b[e];
        for (int j = 0; j < 128; ++j) s3 += hid[j] * f2w[e * 128 + j];
        outp[b * 2 + e] = s3;
    }
}

extern "C" void kernel_launch(void* const* d_in, const int* in_sizes, int n_in,
                              void* d_out, int out_size, void* d_ws, size_t ws_size,
                              hipStream_t stream)
{
    const float* x         = (const float*)d_in[0];
    const float* w_ih0     = (const float*)d_in[1];
    const float* w_hh0     = (const float*)d_in[2];
    const float* b_ih0     = (const float*)d_in[3];
    const float* b_hh0     = (const float*)d_in[4];
    const float* w_ih1     = (const float*)d_in[5];
    const float* w_hh1     = (const float*)d_in[6];
    const float* b_ih1     = (const float*)d_in[7];
    const float* b_hh1     = (const float*)d_in[8];
    const float* gat_W     = (const float*)d_in[9];
    const float* gat_a     = (const float*)d_in[10];
    const float* ln_g      = (const float*)d_in[11];
    const float* ln_b      = (const float*)d_in[12];
    const float* mha_in_w  = (const float*)d_in[13];
    const float* mha_in_b  = (const float*)d_in[14];
    const float* mha_out_w = (const float*)d_in[15];
    const float* mha_out_b = (const float*)d_in[16];
    const float* fc1_w     = (const float*)d_in[17];
    const float* fc1_b     = (const float*)d_in[18];
    const float* fc2_w     = (const float*)d_in[19];
    const float* fc2_b     = (const float*)d_in[20];
    float* out = (float*)d_out;

    float* xpbuf = (float*)d_ws;                       // [B*T][768]  50.3MB
    float* buf1  = xpbuf + (size_t)B_ * T_ * G3_;      // [B*T][256]  16.8MB (h1 / gat / h)
    float* buf2  = buf1 + (size_t)B_ * T_ * H_;        // [B*T][256]  (gru_out)
    float* buf3  = buf2 + (size_t)B_ * T_ * H_;        // [B*T][256]  (hk / o)
    float* W2    = buf3 + (size_t)B_ * T_ * H_;        // 65536
    float* e1    = W2 + 65536;                         // 65536
    float* e2    = e1 + 65536;                         // 65536
    float* opool = e2 + 65536;                         // 4096

    dim3 blk(256);
    // gat_W transpose
    gatw_t<<<dim3(256), blk, 0, stream>>>(gat_W, W2);
    // xp0 = x @ w_ih0^T + b_ih0
    gemm_bias<<<dim3(G3_ / 64, (B_ * T_) / 64), blk, 0, stream>>>(x, w_ih0, b_ih0, xpbuf, B_ * T_, G3_, IN_);
    // GRU layer 0 scan -> buf1
    gru_scan<<<dim3(1), dim3(512), 0, stream>>>(xpbuf, w_hh0, b_hh0, buf1);
    // xp1 = h1 @ w_ih1^T + b_ih1
    gemm_bias<<<dim3(G3_ / 64, (B_ * T_) / 64), blk, 0, stream>>>(buf1, w_ih1, b_ih1, xpbuf, B_ * T_, G3_, H_);
    // GRU layer 1 scan -> buf2 (gru_out)
    gru_scan<<<dim3(1), dim3(512), 0, stream>>>(xpbuf, w_hh1, b_hh1, buf2);
    // hk = gru_out @ W2^T -> buf3
    gemm_bias<<<dim3(H_ / 64, (B_ * T_) / 64), blk, 0, stream>>>(buf2, W2, nullptr, buf3, B_ * T_, H_, H_);
    // e1, e2
    gat_e<<<dim3(8, 4, 16), blk, 0, stream>>>(buf3, gat_a, e1, e2);
    // GAT attention -> buf1
    gat_attn<<<dim3(16, 4, 16), blk, 0, stream>>>(buf3, e1, e2, buf1);
    // h = LN(gru_out + gat) -> buf1 (in place)
    add_ln<<<dim3(B_ * T_), dim3(64), 0, stream>>>(buf2, buf1, ln_g, ln_b, buf1);
    // qkv = h @ mha_in_w^T + b -> xpbuf
    gemm_bias<<<dim3(G3_ / 64, (B_ * T_) / 64), blk, 0, stream>>>(buf1, mha_in_w, mha_in_b, xpbuf, B_ * T_, G3_, H_);
    // MHA -> buf3
    mha_attn<<<dim3(16, 4, 16), blk, 0, stream>>>(xpbuf, buf3);
    // pooled mean over T
    hipMemsetAsync(opool, 0, (size_t)B_ * H_ * sizeof(float), stream);
    pool_mean<<<dim3(128), blk, 0, stream>>>(buf3, opool);
    // head -> out
    head_k<<<dim3(16), blk, 0, stream>>>(opool, mha_out_w, mha_out_b, fc1_w, fc1_b, fc2_w, fc2_b, out);
}

// Round 2
// 3304.218 us; speedup vs baseline: 3.4352x; 3.4352x over previous
//
#include <hip/hip_runtime.h>
#include <hip/hip_bf16.h>

// GNNClassifier: 2x GRU(scan) -> GAT attention -> LN -> MHA -> pool -> FC
// B=16 T=1024 IN=64 H=256 G3=768 K=4 F=64 NH=4 HD=64 C=2

#define B_ 16
#define T_ 1024
#define IN_ 64
#define H_ 256
#define G3_ 768

typedef _Float16 f16x8 __attribute__((ext_vector_type(8)));
typedef float f32x4 __attribute__((ext_vector_type(4)));

__device__ __forceinline__ float fastrcp(float x) { return __builtin_amdgcn_rcpf(x); }
__device__ __forceinline__ float sigmoidf_(float x) { return fastrcp(1.f + __expf(-x)); }
__device__ __forceinline__ float tanh_fast(float x) {
    float t = __expf(-2.f * fabsf(x));
    float r = (1.f - t) * fastrcp(1.f + t);
    return x >= 0.f ? r : -r;
}

// ---------------- generic tiled f32 GEMM: Y[M][N] = X[M][Kd] @ W[N][Kd]^T + bias ----------------
__global__ __launch_bounds__(256) void gemm_bias(
    const float* __restrict__ X, const float* __restrict__ W,
    const float* __restrict__ bias, float* __restrict__ Y,
    int M, int N, int Kd)
{
    __shared__ float As[16][68];   // [k][m]
    __shared__ float Bs[16][68];   // [k][n]
    const int tid = threadIdx.x;
    const int bm = blockIdx.y * 64, bn = blockIdx.x * 64;
    const int tx = tid & 15, ty = tid >> 4;
    const int lr = tid >> 2, lk = (tid & 3) * 4;
    float acc[4][4] = {};
    for (int k0 = 0; k0 < Kd; k0 += 16) {
        float4 va = *(const float4*)(X + (size_t)(bm + lr) * Kd + k0 + lk);
        float4 vb = *(const float4*)(W + (size_t)(bn + lr) * Kd + k0 + lk);
        As[lk + 0][lr] = va.x; As[lk + 1][lr] = va.y; As[lk + 2][lr] = va.z; As[lk + 3][lr] = va.w;
        Bs[lk + 0][lr] = vb.x; Bs[lk + 1][lr] = vb.y; Bs[lk + 2][lr] = vb.z; Bs[lk + 3][lr] = vb.w;
        __syncthreads();
        #pragma unroll
        for (int k = 0; k < 16; ++k) {
            float4 a = *(const float4*)&As[k][ty * 4];
            float4 b = *(const float4*)&Bs[k][tx * 4];
            float av[4] = {a.x, a.y, a.z, a.w};
            float bv[4] = {b.x, b.y, b.z, b.w};
            #pragma unroll
            for (int i = 0; i < 4; ++i)
                #pragma unroll
                for (int j = 0; j < 4; ++j)
                    acc[i][j] += av[i] * bv[j];
        }
        __syncthreads();
    }
    float4 bv4 = bias ? *(const float4*)(bias + bn + tx * 4) : make_float4(0.f, 0.f, 0.f, 0.f);
    #pragma unroll
    for (int i = 0; i < 4; ++i) {
        float4 ov = make_float4(acc[i][0] + bv4.x, acc[i][1] + bv4.y, acc[i][2] + bv4.z, acc[i][3] + bv4.w);
        *(float4*)(Y + (size_t)(bm + ty * 4 + i) * N + bn + tx * 4) = ov;
    }
}

// ---------------- GRU scan: 16 blocks (one per batch), MFMA broadcast-A ----------------
// Per block: gh[768] = w_hh[768][256] @ h[256].  MFMA 16x16x32 f16 with A[m][k]=h[k]
// broadcast over m (all D rows identical -> read reg 0). Wave wv owns units
// [wv*32, wv*32+32) as two 16-col tiles (q=0/1) x 3 gates = 48 MFMAs/wave/step.
// A/B frags share the same (hi,i)->k mapping => correct for any HW k-permutation.
// One raw s_barrier per step (double-buffered h in LDS); only lgkmcnt drained so
// the xp prefetch (t+1) and ys stores stay in flight across the barrier.
__global__ __launch_bounds__(512) void gru_scan(
    const float* __restrict__ xp,   // [B][T][768] (b_ih already added)
    const float* __restrict__ w_hh, // [768][256]
    const float* __restrict__ b_hh, // [768]
    float* __restrict__ ys)         // [B][T][256]
{
    __shared__ _Float16 hbuf[2][272];
    const int b = blockIdx.x;
    const int tid = threadIdx.x;
    const int lane = tid & 63;
    const int wv = tid >> 6;     // wave 0..7
    const int col = lane & 15;   // tile col (n = unit within 16-tile)
    const int hi = lane >> 4;    // 0..3 (k-group)

    // B fragments: weights for this thread's 2 units x 3 gates, f16, in registers
    f16x8 bf[3][2][8];
    float bias_[3][2];
    #pragma unroll
    for (int g = 0; g < 3; ++g) {
        #pragma unroll
        for (int q = 0; q < 2; ++q) {
            const int n = g * 256 + wv * 32 + q * 16 + col;
            bias_[g][q] = b_hh[n];
            #pragma unroll
            for (int c = 0; c < 8; ++c) {
                const float* src = w_hh + (size_t)n * 256 + c * 32 + hi * 8;
                float4 u0 = *(const float4*)(src);
                float4 u1 = *(const float4*)(src + 4);
                f16x8 v;
                v[0] = (_Float16)u0.x; v[1] = (_Float16)u0.y; v[2] = (_Float16)u0.z; v[3] = (_Float16)u0.w;
                v[4] = (_Float16)u1.x; v[5] = (_Float16)u1.y; v[6] = (_Float16)u1.z; v[7] = (_Float16)u1.w;
                bf[g][q][c] = v;
            }
        }
    }
    float hold[2] = {0.f, 0.f};
    if (tid < 256) hbuf[0][tid] = (_Float16)0.f;
    __syncthreads();

    const float* xbase = xp + (size_t)b * T_ * G3_;
    float* ybase = ys + (size_t)b * T_ * H_;

    // prefetch xp(t=0)
    float pref[3][2];
    #pragma unroll
    for (int g = 0; g < 3; ++g)
        #pragma unroll
        for (int q = 0; q < 2; ++q)
            pref[g][q] = xbase[g * 256 + wv * 32 + q * 16 + col];

    int cur = 0;
    for (int t = 0; t < T_; ++t) {
        float xv[3][2];
        #pragma unroll
        for (int g = 0; g < 3; ++g)
            #pragma unroll
            for (int q = 0; q < 2; ++q)
                xv[g][q] = pref[g][q];
        // issue prefetch for t+1 (lands during/after MFMAs)
        const int tn = (t < T_ - 1) ? t + 1 : t;
        #pragma unroll
        for (int g = 0; g < 3; ++g)
            #pragma unroll
            for (int q = 0; q < 2; ++q)
                pref[g][q] = xbase[(size_t)tn * G3_ + g * 256 + wv * 32 + q * 16 + col];

        f32x4 acc[3][2] = {};
        #pragma unroll
        for (int c = 0; c < 8; ++c) {
            f16x8 a = *(const f16x8*)(&hbuf[cur][c * 32 + hi * 8]); // broadcast A (same for all cols)
            #pragma unroll
            for (int g = 0; g < 3; ++g)
                #pragma unroll
                for (int q = 0; q < 2; ++q)
                    acc[g][q] = __builtin_amdgcn_mfma_f32_16x16x32_f16(a, bf[g][q][c], acc[g][q], 0, 0, 0);
        }

        const int nxt = cur ^ 1;
        #pragma unroll
        for (int q = 0; q < 2; ++q) {
            const int unit = wv * 32 + q * 16 + col;
            float ghr = acc[0][q][0] + bias_[0][q];
            float ghz = acc[1][q][0] + bias_[1][q];
            float ghn = acc[2][q][0] + bias_[2][q];
            float r = sigmoidf_(xv[0][q] + ghr);
            float z = sigmoidf_(xv[1][q] + ghz);
            float nn = tanh_fast(xv[2][q] + r * ghn);
            float hv = (1.f - z) * nn + z * hold[q];
            hold[q] = hv;
            if (hi == 0) {
                ybase[(size_t)t * H_ + unit] = hv;      // coalesced 16-lane store
                hbuf[nxt][unit] = (_Float16)hv;
            }
        }
        // raw barrier: drain LDS only; keep xp prefetch + ys stores in flight
        asm volatile("s_waitcnt lgkmcnt(0)" ::: "memory");
        __builtin_amdgcn_s_barrier();
        asm volatile("" ::: "memory");
        cur = nxt;
    }
}

// ---------------- gat_W (K,H,F) -> W2[(k*64+f)][d] ----------------
__global__ void gatw_t(const float* __restrict__ gw, float* __restrict__ W2)
{
    int idx = blockIdx.x * 256 + threadIdx.x; // 65536
    int n = idx >> 8, d = idx & 255;
    W2[idx] = gw[(size_t)(n >> 6) * 16384 + (size_t)d * 64 + (n & 63)];
}

// ---------------- e1/e2: [b][k][t] = sum_f hk[b][t][k*64+f] * a{1,2}[k][f] ----------------
__global__ __launch_bounds__(256) void gat_e(
    const float* __restrict__ hk, const float* __restrict__ ga,
    float* __restrict__ e1, float* __restrict__ e2)
{
    __shared__ float tile[128][65];
    __shared__ float a1s[64], a2s[64];
    const int tt = blockIdx.x, k = blockIdx.y, b = blockIdx.z; // grid (8,4,16)
    const int tid = threadIdx.x;
    if (tid < 64) { a1s[tid] = ga[k * 128 + tid]; a2s[tid] = ga[k * 128 + 64 + tid]; }
    #pragma unroll
    for (int rep = 0; rep < 32; ++rep) {
        int idx = rep * 256 + tid; int tl = idx >> 6, f = idx & 63;
        tile[tl][f] = hk[((size_t)(b * 1024 + tt * 128 + tl)) * 256 + k * 64 + f];
    }
    __syncthreads();
    if (tid < 128) {
        float s1 = 0.f, s2 = 0.f;
        #pragma unroll 8
        for (int f = 0; f < 64; ++f) {
            float hv = tile[tid][f];
            s1 += hv * a1s[f]; s2 += hv * a2s[f];
        }
        const size_t o = (size_t)(b * 4 + k) * 1024 + tt * 128 + tid;
        e1[o] = s1; e2[o] = s2;
    }
}

// ---------------- GAT attention: out[b][t][k*64+f] = sum_s softmax_s(leaky(e1[t]+e2[s])) * hk[b][s][k*64+f] ----
__global__ __launch_bounds__(256) void gat_attn(
    const float* __restrict__ hk, const float* __restrict__ e1,
    const float* __restrict__ e2, float* __restrict__ outp)
{
    __shared__ float hks[64][64];
    __shared__ float wsld[64][65];
    __shared__ float e2s[64];
    __shared__ float e1s[64];
    __shared__ float ms[64];
    __shared__ float ls[64];
    const int tt = blockIdx.x, k = blockIdx.y, b = blockIdx.z; // grid (16,4,16)
    const int tid = threadIdx.x;
    const int t0 = tt * 64;
    const float* e2row = e2 + (size_t)(b * 4 + k) * 1024;
    if (tid < 64) { e1s[tid] = e1[(size_t)(b * 4 + k) * 1024 + t0 + tid]; ls[tid] = 0.f; }
    __syncthreads();
    // pass A: exact row max (scores are cheap: e1[t]+e2[s])
    {
        const int t = tid & 63, grp = tid >> 6;
        const float ev1 = e1s[t];
        float m = -3.4e38f;
        for (int s = grp; s < 1024; s += 4) {
            float e = ev1 + e2row[s];
            e = (e > 0.f) ? e : 0.2f * e;
            m = fmaxf(m, e);
        }
        wsld[t][grp] = m;
    }
    __syncthreads();
    if (tid < 64) ms[tid] = fmaxf(fmaxf(wsld[tid][0], wsld[tid][1]), fmaxf(wsld[tid][2], wsld[tid][3]));
    __syncthreads();
    float acc[16] = {};
    const int tB = tid & 63, fq = tid >> 6;
    const int tA = tid >> 2, sq = tid & 3;
    const float e1A = e1s[tA];
    const float mA = ms[tA];
    for (int st = 0; st < 16; ++st) {
        #pragma unroll
        for (int rep = 0; rep < 16; ++rep) {
            int idx = rep * 256 + tid; int sl = idx >> 6, f = idx & 63;
            hks[sl][f] = hk[((size_t)(b * 1024 + st * 64 + sl)) * 256 + k * 64 + f];
        }
        if (tid < 64) e2s[tid] = e2row[st * 64 + tid];
        __syncthreads();
        {
            float lsum = 0.f;
            #pragma unroll
            for (int i = 0; i < 16; ++i) {
                int s = sq * 16 + i;
                float e = e1A + e2s[s];
                e = (e > 0.f) ? e : 0.2f * e;
                float wvv = __expf(e - mA);
                wsld[tA][s] = wvv;
                lsum += wvv;
            }
            lsum += __shfl_xor(lsum, 1);
            lsum += __shfl_xor(lsum, 2);
            if (sq == 0) ls[tA] += lsum;
        }
        __syncthreads();
        #pragma unroll 8
        for (int i = 0; i < 64; ++i) {
            float wvv = wsld[tB][i];
            const float4 v0 = *(const float4*)&hks[i][fq * 16 + 0];
            const float4 v1 = *(const float4*)&hks[i][fq * 16 + 4];
            const float4 v2 = *(const float4*)&hks[i][fq * 16 + 8];
            const float4 v3 = *(const float4*)&hks[i][fq * 16 + 12];
            acc[0] += wvv * v0.x; acc[1] += wvv * v0.y; acc[2] += wvv * v0.z; acc[3] += wvv * v0.w;
            acc[4] += wvv * v1.x; acc[5] += wvv * v1.y; acc[6] += wvv * v1.z; acc[7] += wvv * v1.w;
            acc[8] += wvv * v2.x; acc[9] += wvv * v2.y; acc[10] += wvv * v2.z; acc[11] += wvv * v2.w;
            acc[12] += wvv * v3.x; acc[13] += wvv * v3.y; acc[14] += wvv * v3.z; acc[15] += wvv * v3.w;
        }
        __syncthreads();
    }
    const float inv = 1.f / ls[tB];
    float* po = outp + ((size_t)(b * 1024 + t0 + tB)) * 256 + k * 64 + fq * 16;
    #pragma unroll
    for (int j2 = 0; j2 < 16; j2 += 4) {
        float4 ov = make_float4(acc[j2] * inv, acc[j2 + 1] * inv, acc[j2 + 2] * inv, acc[j2 + 3] * inv);
        *(float4*)(po + j2) = ov;
    }
}

// ---------------- residual + LayerNorm (in-place safe: row held in regs) ----------------
__global__ __launch_bounds__(64) void add_ln(
    const float* __restrict__ a, const float* bb,
    const float* __restrict__ gamma, const float* __restrict__ beta,
    float* outp)
{
    const int row = blockIdx.x;
    const int lane = threadIdx.x;
    const size_t base = (size_t)row * 256 + lane * 4;
    float4 va = *(const float4*)(a + base);
    float4 vb = *(const float4*)(bb + base);
    float xv[4] = {va.x + vb.x, va.y + vb.y, va.z + vb.z, va.w + vb.w};
    float s = xv[0] + xv[1] + xv[2] + xv[3];
    float s2 = xv[0] * xv[0] + xv[1] * xv[1] + xv[2] * xv[2] + xv[3] * xv[3];
    #pragma unroll
    for (int off = 32; off >= 1; off >>= 1) {
        s += __shfl_xor(s, off);
        s2 += __shfl_xor(s2, off);
    }
    const float mu = s * (1.f / 256.f);
    const float var = s2 * (1.f / 256.f) - mu * mu;
    const float rs = rsqrtf(var + 1e-5f);
    float4 g4 = *(const float4*)(gamma + lane * 4);
    float4 b4 = *(const float4*)(beta + lane * 4);
    float4 ov;
    ov.x = (xv[0] - mu) * rs * g4.x + b4.x;
    ov.y = (xv[1] - mu) * rs * g4.y + b4.y;
    ov.z = (xv[2] - mu) * rs * g4.z + b4.z;
    ov.w = (xv[3] - mu) * rs * g4.w + b4.w;
    *(float4*)(outp + base) = ov;
}

// ---------------- MHA flash attention over qkv [b][t][768] ----------------
__global__ __launch_bounds__(256) void mha_attn(const float* __restrict__ qkv, float* __restrict__ o)
{
    __shared__ float qs[64][68];
    __shared__ float kvs[64][68];   // holds K during scores, then V during PV
    __shared__ float wsld[64][65];
    __shared__ float ms[64], ls[64], cs[64];
    const int tt = blockIdx.x, h = blockIdx.y, b = blockIdx.z; // grid (16,4,16)
    const int tid = threadIdx.x;
    const int t0 = tt * 64;
    #pragma unroll
    for (int rep = 0; rep < 16; ++rep) {
        int idx = rep * 256 + tid; int tl = idx >> 6, f = idx & 63;
        qs[tl][f] = qkv[((size_t)(b * 1024 + t0 + tl)) * 768 + h * 64 + f];
    }
    if (tid < 64) { ms[tid] = -3.4e38f; ls[tid] = 0.f; }
    float acc[16] = {};
    const int tB = tid & 63, fq = tid >> 6;
    const int tA = tid >> 2, sq = tid & 3;
    __syncthreads();
    for (int st = 0; st < 16; ++st) {
        #pragma unroll
        for (int rep = 0; rep < 16; ++rep) {
            int idx = rep * 256 + tid; int sl = idx >> 6, f = idx & 63;
            kvs[sl][f] = qkv[((size_t)(b * 1024 + st * 64 + sl)) * 768 + 256 + h * 64 + f];
        }
        __syncthreads();
        float sc[16] = {};
        #pragma unroll
        for (int dc = 0; dc < 4; ++dc) {
            float4 q0 = *(const float4*)&qs[tA][dc * 16 + 0];
            float4 q1 = *(const float4*)&qs[tA][dc * 16 + 4];
            float4 q2 = *(const float4*)&qs[tA][dc * 16 + 8];
            float4 q3 = *(const float4*)&qs[tA][dc * 16 + 12];
            #pragma unroll
            for (int i = 0; i < 16; ++i) {
                const int s = sq * 16 + i;
                float4 k0 = *(const float4*)&kvs[s][dc * 16 + 0];
                float4 k1 = *(const float4*)&kvs[s][dc * 16 + 4];
                float4 k2 = *(const float4*)&kvs[s][dc * 16 + 8];
                float4 k3 = *(const float4*)&kvs[s][dc * 16 + 12];
                sc[i] += q0.x * k0.x + q0.y * k0.y + q0.z * k0.z + q0.w * k0.w
                       + q1.x * k1.x + q1.y * k1.y + q1.z * k1.z + q1.w * k1.w
                       + q2.x * k2.x + q2.y * k2.y + q2.z * k2.z + q2.w * k2.w
                       + q3.x * k3.x + q3.y * k3.y + q3.z * k3.z + q3.w * k3.w;
            }
        }
        float tmax = -3.4e38f;
        #pragma unroll
        for (int i = 0; i < 16; ++i) { sc[i] *= 0.125f; tmax = fmaxf(tmax, sc[i]); }
        tmax = fmaxf(tmax, __shfl_xor(tmax, 1));
        tmax = fmaxf(tmax, __shfl_xor(tmax, 2));
        float mold = ms[tA];
        float mnew = fmaxf(mold, tmax);
        float corrv = __expf(mold - mnew);
        float lsum = 0.f;
        #pragma unroll
        for (int i = 0; i < 16; ++i) {
            float wvv = __expf(sc[i] - mnew);
            wsld[tA][sq * 16 + i] = wvv;
            lsum += wvv;
        }
        lsum += __shfl_xor(lsum, 1);
        lsum += __shfl_xor(lsum, 2);
        if (sq == 0) { ls[tA] = ls[tA] * corrv + lsum; ms[tA] = mnew; cs[tA] = corrv; }
        __syncthreads();
        #pragma unroll
        for (int rep = 0; rep < 16; ++rep) {
            int idx = rep * 256 + tid; int sl = idx >> 6, f = idx & 63;
            kvs[sl][f] = qkv[((size_t)(b * 1024 + st * 64 + sl)) * 768 + 512 + h * 64 + f];
        }
        __syncthreads();
        {
            const float cr = cs[tB];
            #pragma unroll
            for (int j2 = 0; j2 < 16; ++j2) acc[j2] *= cr;
            #pragma unroll 8
            for (int i = 0; i < 64; ++i) {
                float wvv = wsld[tB][i];
                const float4 v0 = *(const float4*)&kvs[i][fq * 16 + 0];
                const float4 v1 = *(const float4*)&kvs[i][fq * 16 + 4];
                const float4 v2 = *(const float4*)&kvs[i][fq * 16 + 8];
                const float4 v3 = *(const float4*)&kvs[i][fq * 16 + 12];
                acc[0] += wvv * v0.x; acc[1] += wvv * v0.y; acc[2] += wvv * v0.z; acc[3] += wvv * v0.w;
                acc[4] += wvv * v1.x; acc[5] += wvv * v1.y; acc[6] += wvv * v1.z; acc[7] += wvv * v1.w;
                acc[8] += wvv * v2.x; acc[9] += wvv * v2.y; acc[10] += wvv * v2.z; acc[11] += wvv * v2.w;
                acc[12] += wvv * v3.x; acc[13] += wvv * v3.y; acc[14] += wvv * v3.z; acc[15] += wvv * v3.w;
            }
        }
        __syncthreads();
    }
    const float inv = 1.f / ls[tB];
    float* po = o + ((size_t)(b * 1024 + t0 + tB)) * 256 + h * 64 + fq * 16;
    #pragma unroll
    for (int j2 = 0; j2 < 16; j2 += 4) {
        float4 ov = make_float4(acc[j2] * inv, acc[j2 + 1] * inv, acc[j2 + 2] * inv, acc[j2 + 3] * inv);
        *(float4*)(po + j2) = ov;
    }
}

// ---------------- mean over T (pooling commuted before output projection) ----------------
__global__ __launch_bounds__(256) void pool_mean(const float* __restrict__ o, float* __restrict__ opool)
{
    const int b = blockIdx.x >> 3, chunk = blockIdx.x & 7;
    const int d = threadIdx.x;
    float s = 0.f;
    for (int t = chunk * 128; t < chunk * 128 + 128; ++t)
        s += o[((size_t)(b * 1024 + t)) * 256 + d];
    atomicAdd(&opool[b * 256 + d], s * (1.f / 1024.f));
}

// ---------------- head: out_proj(pooled) -> fc1 relu -> fc2 ----------------
__global__ __launch_bounds__(256) void head_k(
    const float* __restrict__ opool, const float* __restrict__ wout, const float* __restrict__ bout,
    const float* __restrict__ f1w, const float* __restrict__ f1b,
    const float* __restrict__ f2w, const float* __restrict__ f2b,
    float* __restrict__ outp)
{
    __shared__ float op[256], pooled[256], hid[128];
    const int b = blockIdx.x, e = threadIdx.x;
    op[e] = opool[b * 256 + e];
    __syncthreads();
    float s = bout[e];
    for (int d = 0; d < 256; d += 4) {
        float4 w4 = *(const float4*)(wout + (size_t)e * 256 + d);
        s += op[d] * w4.x + op[d + 1] * w4.y + op[d + 2] * w4.z + op[d + 3] * w4.w;
    }
    pooled[e] = s;
    __syncthreads();
    if (e < 128) {
        float s2 = f1b[e];
        for (int d = 0; d < 256; d += 4) {
            float4 w4 = *(const float4*)(f1w + (size_t)e * 256 + d);
            s2 += pooled[d] * w4.x + pooled[d + 1] * w4.y + pooled[d + 2] * w4.z + pooled[d + 3] * w4.w;
        }
        hid[e] = fmaxf(s2, 0.f);
    }
    __syncthreads();
    if (e < 2) {
        float s3 = f2b[e];
        for (int j = 0; j < 128; ++j) s3 += hid[j] * f2w[e * 128 + j];
        outp[b * 2 + e] = s3;
    }
}

extern "C" void kernel_launch(void* const* d_in, const int* in_sizes, int n_in,
                              void* d_out, int out_size, void* d_ws, size_t ws_size,
                              hipStream_t stream)
{
    const float* x         = (const float*)d_in[0];
    const float* w_ih0     = (const float*)d_in[1];
    const float* w_hh0     = (const float*)d_in[2];
    const float* b_ih0     = (const float*)d_in[3];
    const float* b_hh0     = (const float*)d_in[4];
    const float* w_ih1     = (const float*)d_in[5];
    const float* w_hh1     = (const float*)d_in[6];
    const float* b_ih1     = (const float*)d_in[7];
    const float* b_hh1     = (const float*)d_in[8];
    const float* gat_W     = (const float*)d_in[9];
    const float* gat_a     = (const float*)d_in[10];
    const float* ln_g      = (const float*)d_in[11];
    const float* ln_b      = (const float*)d_in[12];
    const float* mha_in_w  = (const float*)d_in[13];
    const float* mha_in_b  = (const float*)d_in[14];
    const float* mha_out_w = (const float*)d_in[15];
    const float* mha_out_b = (const float*)d_in[16];
    const float* fc1_w     = (const float*)d_in[17];
    const float* fc1_b     = (const float*)d_in[18];
    const float* fc2_w     = (const float*)d_in[19];
    const float* fc2_b     = (const float*)d_in[20];
    float* out = (float*)d_out;

    float* xpbuf = (float*)d_ws;                       // [B*T][768]  50.3MB
    float* buf1  = xpbuf + (size_t)B_ * T_ * G3_;      // [B*T][256]  16.8MB (h1 / gat / h)
    float* buf2  = buf1 + (size_t)B_ * T_ * H_;        // [B*T][256]  (gru_out)
    float* buf3  = buf2 + (size_t)B_ * T_ * H_;        // [B*T][256]  (hk / o)
    float* W2    = buf3 + (size_t)B_ * T_ * H_;        // 65536
    float* e1    = W2 + 65536;                         // 65536
    float* e2    = e1 + 65536;                         // 65536
    float* opool = e2 + 65536;                         // 4096

    dim3 blk(256);
    // gat_W transpose
    gatw_t<<<dim3(256), blk, 0, stream>>>(gat_W, W2);
    // xp0 = x @ w_ih0^T + b_ih0
    gemm_bias<<<dim3(G3_ / 64, (B_ * T_) / 64), blk, 0, stream>>>(x, w_ih0, b_ih0, xpbuf, B_ * T_, G3_, IN_);
    // GRU layer 0 scan -> buf1 (16 blocks, one per batch)
    gru_scan<<<dim3(16), dim3(512), 0, stream>>>(xpbuf, w_hh0, b_hh0, buf1);
    // xp1 = h1 @ w_ih1^T + b_ih1
    gemm_bias<<<dim3(G3_ / 64, (B_ * T_) / 64), blk, 0, stream>>>(buf1, w_ih1, b_ih1, xpbuf, B_ * T_, G3_, H_);
    // GRU layer 1 scan -> buf2 (gru_out)
    gru_scan<<<dim3(16), dim3(512), 0, stream>>>(xpbuf, w_hh1, b_hh1, buf2);
    // hk = gru_out @ W2^T -> buf3
    gemm_bias<<<dim3(H_ / 64, (B_ * T_) / 64), blk, 0, stream>>>(buf2, W2, nullptr, buf3, B_ * T_, H_, H_);
    // e1, e2
    gat_e<<<dim3(8, 4, 16), blk, 0, stream>>>(buf3, gat_a, e1, e2);
    // GAT attention -> buf1
    gat_attn<<<dim3(16, 4, 16), blk, 0, stream>>>(buf3, e1, e2, buf1);
    // h = LN(gru_out + gat) -> buf1 (in place)
    add_ln<<<dim3(B_ * T_), dim3(64), 0, stream>>>(buf2, buf1, ln_g, ln_b, buf1);
    // qkv = h @ mha_in_w^T + b -> xpbuf
    gemm_bias<<<dim3(G3_ / 64, (B_ * T_) / 64), blk, 0, stream>>>(buf1, mha_in_w, mha_in_b, xpbuf, B_ * T_, G3_, H_);
    // MHA -> buf3
    mha_attn<<<dim3(16, 4, 16), blk, 0, stream>>>(xpbuf, buf3);
    // pooled mean over T
    hipMemsetAsync(opool, 0, (size_t)B_ * H_ * sizeof(float), stream);
    pool_mean<<<dim3(128), blk, 0, stream>>>(buf3, opool);
    // head -> out
    head_k<<<dim3(16), blk, 0, stream>>>(opool, mha_out_w, mha_out_b, fc1_w, fc1_b, fc2_w, fc2_b, out);
}